// Round 10
// baseline (5776.755 us; speedup 1.0000x reference)
//
#include <hip/hip_runtime.h>

// GRU T=512 B=256 D=512 H=512 O=256
// R10: calibrated two-config kernel.
//  FAST (requires unanimous calibration pass): xcd-grouping (wgid&7), all
//    exchange L2-local: plain write-through publishes, plain flag stores,
//    polls and consumes via {vmcnt(0); buffer_inv sc1; vmcnt(0)} + plain loads.
//    No atomics in the steady state (R8 showed contended RMW polls).
//  SLOW (any calibration failure): bit-exact R3 configuration — grouping
//    bg=wgid>>3 / cg=wgid&7, AGENT(sc0sc1) atomics for publish/flag/consume —
//    the proven 5.9 us/step path.
// Grouping is chosen AFTER a global unanimity vote (SYSTEM-relaxed rendezvous,
// R2-proven). Calibration: flag ping-pong + stale-L1 data round-trip (rounds
// 2-3 re-read an L1-resident line after inv). All spins bounded.

#define T_ 512
#define B_ 256
#define D_ 512
#define H_ 512
#define O_ 256

#define NWG 128
#define ROWS 16
#define GC 64
#define GRP 8
#define FBASE 8
#define ECELL 12288
#define DBASE 12352
#define GCELL 16448

typedef __attribute__((ext_vector_type(8))) short short8;
typedef __attribute__((ext_vector_type(4))) float f32x4;
typedef __attribute__((ext_vector_type(4))) unsigned int uint4v;

__device__ __forceinline__ unsigned short f2bf(float f) {
  unsigned u = __float_as_uint(f);
  u = (u + 0x7FFFu + ((u >> 16) & 1u)) >> 16;   // RNE
  return (unsigned short)u;
}
__device__ __forceinline__ float bf2f(unsigned short h) {
  return __uint_as_float(((unsigned)h) << 16);
}
__device__ __forceinline__ int ready(unsigned v, unsigned t) { return (v - t) < 64u; }

// Drain VMEM, invalidate vector L1, wait for the invalidate, fence scheduling.
__device__ __forceinline__ void inv_l1() {
  asm volatile("s_waitcnt vmcnt(0)\n\tbuffer_inv sc1\n\ts_waitcnt vmcnt(0)" ::: "memory");
  __builtin_amdgcn_sched_barrier(0);
}

// ---- prep: transpose weights, combine biases, bump epoch, zero global cells
__global__ void prep_kernel(const float* wz, const float* uz,
                            const float* wr, const float* ur,
                            const float* wh, const float* uh,
                            const float* bz, const float* ubz,
                            const float* br, const float* ubr,
                            const float* bh, const float* ubh,
                            unsigned short* WT, unsigned short* UT,
                            float* cb, int* bar)
{
  int idx = blockIdx.x * 256 + threadIdx.x;
  if (idx < 1536 * 512) {
    int n = idx >> 9;
    int k = idx & 511;
    int g = n >> 9;
    int c = n & 511;
    const float* w = (g == 0) ? wz : (g == 1) ? wr : wh;
    const float* u = (g == 0) ? uz : (g == 1) ? ur : uh;
    WT[idx] = f2bf(w[k * H_ + c]);
    UT[idx] = f2bf(u[k * H_ + c]);
  }
  if (idx < 1536) {
    int g = idx >> 9, c = idx & 511;
    const float* b  = (g == 0) ? bz  : (g == 1) ? br  : bh;
    const float* ub = (g == 0) ? ubz : (g == 1) ? ubr : ubh;
    cb[idx] = b[c] + ub[c];
  }
  if (idx < 64) bar[GCELL + idx] = 0;   // global vote cells (in-graph, ordered)
  if (blockIdx.x == 0 && threadIdx.x == 0)
    __hip_atomic_fetch_add(&bar[ECELL], 1, __ATOMIC_RELAXED, __HIP_MEMORY_SCOPE_SYSTEM);
}

// ---- persistent scan kernel (+ fused FC epilogue)
__global__ __launch_bounds__(256, 1) void gru_scan(
    const float* __restrict__ x,
    const unsigned short* __restrict__ WT,
    const unsigned short* __restrict__ UT,
    const float* __restrict__ cb,
    unsigned short* hbuf,
    unsigned short* rhbuf,
    int* bar,
    const float* __restrict__ fcw,
    const float* __restrict__ fcb,
    float* __restrict__ out)
{
  __shared__ __align__(16) unsigned short x_lds[2][ROWS][520];
  __shared__ __align__(16) unsigned short h_lds[ROWS][520];
  __shared__ __align__(8)  unsigned short pub[ROWS][GC];
  __shared__ int s_ok, s_fast;
  __shared__ unsigned s_base;

  const int tid = threadIdx.x;
  const int wid = tid >> 6;
  const int lane = tid & 63;
  const int l16 = lane & 15;
  const int lhi = lane >> 4;

  const int wgid = blockIdx.x;
  // tentative xcd grouping (validated by calibration)
  const int xbg = (wgid & 7) * 2 + ((wgid >> 3) >> 3);
  const int xcg = (wgid >> 3) & 7;

  int* fastf = bar + 4096 + xbg * 256;
  int* obsf  = bar + 8192 + xbg * 256;
  int* dataf = bar + DBASE + xbg * 256;

  if (tid == 0)
    s_base = ((unsigned)__hip_atomic_load(&bar[ECELL], __ATOMIC_RELAXED,
                                          __HIP_MEMORY_SCOPE_SYSTEM)) << 13;
  __syncthreads();
  const unsigned base = s_base;

  // ---- calibration: plain-store flags + inv/plain polls + data round-trip ----
  if (tid == 0) s_ok = 1;
  __syncthreads();
  for (int r = 1; r <= 3; ++r) {
    if (wid == 0) {
      if (lane == 0) {
        uint4v dv = { base + r, base + r + 101u, base + r + 202u, base + r + 303u };
        *(uint4v*)(dataf + xcg * 32) = dv;                       // plain data store
        asm volatile("s_waitcnt vmcnt(0)" ::: "memory");          // data at L2
        *(fastf + xcg * 32) = (int)(base + r);                    // plain flag store
      }
      int vote = 1;
      if (lane < GRP) {
        const int* p = fastf + lane * 32;
        int lim = 0;
        const int bound = (r == 1) ? 2048 : 1024;
        for (;;) {
          inv_l1();
          unsigned v = *(const volatile unsigned*)p;  // volatile: no CSE; L1 fresh via inv
          if (ready(v, base + r)) break;
          if (++lim > bound) { vote = 0; break; }
        }
      }
      inv_l1();
      if (lane < GRP && vote) {
        uint4v dv = *(const uint4v*)(dataf + lane * 32);          // plain load
        if (dv.x != base + r || dv.y != base + r + 101u ||
            dv.z != base + r + 202u || dv.w != base + r + 303u) vote = 0;
      }
      unsigned long long b = __ballot(vote);
      if (lane == 0) { if ((b & 0xFFull) != 0xFFull) s_ok = 0; }
    }
    __syncthreads();
  }
  // per-group consensus (proven AGENT path)
  if (tid == 0)
    __hip_atomic_store(obsf + xcg * 32, (int)(base + (s_ok ? 2 : 1)),
                       __ATOMIC_RELAXED, __HIP_MEMORY_SCOPE_AGENT);
  if (wid == 0) {
    int vote = 1;
    if (lane < GRP) {
      int lim = 0; unsigned v;
      for (;;) {
        v = (unsigned)__hip_atomic_load(obsf + lane * 32,
                                        __ATOMIC_RELAXED, __HIP_MEMORY_SCOPE_AGENT);
        if (ready(v, base + 1)) break;
        if (++lim > (1 << 20)) { v = base + 1; break; }
        __builtin_amdgcn_s_sleep(1);
      }
      vote = (v == base + 2);
    }
    unsigned long long b = __ballot(vote);
    if (lane == 0) s_fast = ((b & 0xFFull) == 0xFFull) ? 1 : 0;
  }
  __syncthreads();

  // ---- global unanimity vote (SYSTEM rendezvous, R2-proven) ----
  if (tid == 0) {
    __hip_atomic_fetch_add(&bar[GCELL + 16], s_fast ? 1 : 0,
                           __ATOMIC_RELAXED, __HIP_MEMORY_SCOPE_SYSTEM);
    __hip_atomic_fetch_add(&bar[GCELL], 1,
                           __ATOMIC_RELAXED, __HIP_MEMORY_SCOPE_SYSTEM);
    int spins = 0;
    while (__hip_atomic_load(&bar[GCELL], __ATOMIC_RELAXED,
                             __HIP_MEMORY_SCOPE_SYSTEM) < NWG) {
      __builtin_amdgcn_s_sleep(2);
      if (++spins > (1 << 22)) break;
    }
    int a = __hip_atomic_load(&bar[GCELL + 16], __ATOMIC_RELAXED,
                              __HIP_MEMORY_SCOPE_SYSTEM);
    s_fast = (a == NWG) ? 1 : 0;
  }
  __syncthreads();
  const int fast = s_fast;

  // ---- final grouping: fast -> xcd groups; slow -> EXACT R3 grouping ----
  const int bg = fast ? xbg : (wgid >> 3);
  const int cg = fast ? xcg : (wgid & 7);
  const int r0 = bg * ROWS;
  const int c0 = cg * GC;

  int* slowf  = bar + bg * 256;
  int* myslow = slowf + cg * 32;
  int* grpff  = bar + 4096 + bg * 256;   // == fastf in fast mode
  int* myfast = grpff + cg * 32;

  const int ct = c0 + wid * 16;
  const unsigned short* WTz = WT + (size_t)(ct)        * 512;
  const unsigned short* WTr = WT + (size_t)(512 + ct)  * 512;
  const unsigned short* WTh = WT + (size_t)(1024 + ct) * 512;
  const unsigned short* UTz = UT + (size_t)(ct)        * 512;
  const unsigned short* UTr = UT + (size_t)(512 + ct)  * 512;
  const unsigned short* UTh = UT + (size_t)(1024 + ct) * 512;

  const int gcz  = ct + l16;
  const int lcol = ct - c0 + l16;
  const float cbz = cb[gcz];
  const float cbr = cb[512 + gcz];
  const float cbh = cb[1024 + gcz];

  short8 uzr[16], urr[16], uhr[16];
  #pragma unroll
  for (int k = 0; k < 16; ++k) {
    const int off = l16 * 512 + k * 32 + lhi * 8;
    uzr[k] = *(const short8*)(UTz + off);
    urr[k] = *(const short8*)(UTr + off);
    uhr[k] = *(const short8*)(UTh + off);
  }

  float4 xr4[8];
  {
    const float4* xs = (const float4*)(x + (size_t)r0 * D_);
    #pragma unroll
    for (int i = 0; i < 8; ++i) {
      int g = tid + i * 256;
      float4 v = xs[(g >> 7) * 128 + (g & 127)];
      unsigned short tmp[4] = { f2bf(v.x), f2bf(v.y), f2bf(v.z), f2bf(v.w) };
      *(unsigned long long*)&x_lds[0][g >> 7][(g & 127) * 4] = *(unsigned long long*)tmp;
      *(unsigned long long*)&h_lds[g >> 7][(g & 127) * 4] = 0ull;
    }
    const float4* xs1 = (const float4*)(x + ((size_t)B_ + r0) * D_);
    #pragma unroll
    for (int i = 0; i < 8; ++i) {
      int g = tid + i * 256;
      xr4[i] = xs1[(g >> 7) * 128 + (g & 127)];
    }
  }
  __syncthreads();

  f32x4 xzc = {0.f,0.f,0.f,0.f}, xrc = {0.f,0.f,0.f,0.f}, xhc = {0.f,0.f,0.f,0.f};
  {
    const unsigned short* xrow = &x_lds[0][l16][0];
    #pragma unroll
    for (int k = 0; k < 16; ++k) {
      int ko = k * 32 + lhi * 8;
      short8 ax = *(const short8*)(xrow + ko);
      int boff = l16 * 512 + ko;
      short8 wz = *(const short8*)(WTz + boff);
      short8 wr = *(const short8*)(WTr + boff);
      short8 wh = *(const short8*)(WTh + boff);
      xzc = __builtin_amdgcn_mfma_f32_16x16x32_bf16(ax, wz, xzc, 0, 0, 0);
      xrc = __builtin_amdgcn_mfma_f32_16x16x32_bf16(ax, wr, xrc, 0, 0, 0);
      xhc = __builtin_amdgcn_mfma_f32_16x16x32_bf16(ax, wh, xhc, 0, 0, 0);
    }
  }

  for (int t = 0; t < T_; ++t) {
    const int p = t & 1;
    // ---- phase A ----
    f32x4 accz = {0.f,0.f,0.f,0.f};
    f32x4 accr = {0.f,0.f,0.f,0.f};
    {
      const unsigned short* hrow = &h_lds[l16][0];
      #pragma unroll
      for (int k = 0; k < 16; ++k) {
        short8 ah = *(const short8*)(hrow + k * 32 + lhi * 8);
        accz = __builtin_amdgcn_mfma_f32_16x16x32_bf16(ah, uzr[k], accz, 0, 0, 0);
        accr = __builtin_amdgcn_mfma_f32_16x16x32_bf16(ah, urr[k], accr, 0, 0, 0);
      }
    }
    f32x4 z4, gh4;
    #pragma unroll
    for (int i = 0; i < 4; ++i) {
      int lrow = lhi * 4 + i;
      float h_old = bf2f(h_lds[lrow][gcz]);
      float zv = 1.f / (1.f + __expf(-(accz[i] + xzc[i] + cbz)));
      float rv = 1.f / (1.f + __expf(-(accr[i] + xrc[i] + cbr)));
      z4[i]  = zv;
      gh4[i] = (1.f - zv) * h_old;
      pub[lrow][lcol] = f2bf(rv * h_old);
    }
    __syncthreads();
    // ---- publish rh; overlap x-stage; drain; flag ----
    {
      int row = tid >> 4, c4 = (tid & 15) * 4;
      unsigned long long v = *(const unsigned long long*)&pub[row][c4];
      unsigned long long* dst = (unsigned long long*)
          (rhbuf + (size_t)(r0 + row) * H_ + c0 + c4);
      if (fast) *dst = v;
      else __hip_atomic_store(dst, v, __ATOMIC_RELAXED, __HIP_MEMORY_SCOPE_AGENT);
    }
    #pragma unroll
    for (int i = 0; i < 8; ++i) {
      int g = tid + i * 256;
      float4 v = xr4[i];
      unsigned short tmp[4] = { f2bf(v.x), f2bf(v.y), f2bf(v.z), f2bf(v.w) };
      *(unsigned long long*)&x_lds[p ^ 1][g >> 7][(g & 127) * 4] = *(unsigned long long*)tmp;
    }
    asm volatile("s_waitcnt vmcnt(0)" ::: "memory");
    __syncthreads();
    if (tid == 0) {
      if (fast) *myfast = (int)(base + FBASE + 2 * t + 1);
      else __hip_atomic_store(myslow, (int)(base + FBASE + 2 * t + 1),
                              __ATOMIC_RELAXED, __HIP_MEMORY_SCOPE_AGENT);
    }

    // ---- bubbles: xz_next, xr_next ----
    f32x4 xzn = {0.f,0.f,0.f,0.f}, xrn = {0.f,0.f,0.f,0.f}, xhn = {0.f,0.f,0.f,0.f};
    {
      const unsigned short* xrow = &x_lds[p ^ 1][l16][0];
      #pragma unroll
      for (int k = 0; k < 16; ++k) {
        int ko = k * 32 + lhi * 8;
        short8 ax = *(const short8*)(xrow + ko);
        short8 wz = *(const short8*)(WTz + l16 * 512 + ko);
        short8 wr = *(const short8*)(WTr + l16 * 512 + ko);
        xzn = __builtin_amdgcn_mfma_f32_16x16x32_bf16(ax, wz, xzn, 0, 0, 0);
        xrn = __builtin_amdgcn_mfma_f32_16x16x32_bf16(ax, wr, xrn, 0, 0, 0);
      }
    }
    // ---- wait barrier 1 ----
    if (tid < GRP) {
      int lim = 0;
      if (fast) {
        const volatile unsigned* p1 = (const volatile unsigned*)(grpff + tid * 32);
        for (;;) {
          inv_l1();
          if (ready(*p1, base + FBASE + 2 * t + 1)) break;
          if (++lim > (1 << 14)) break;
        }
      } else {
        int* p1 = slowf + tid * 32;
        while (!ready((unsigned)__hip_atomic_load(p1, __ATOMIC_RELAXED,
                                                  __HIP_MEMORY_SCOPE_AGENT),
                      base + FBASE + 2 * t + 1))
          { if (++lim > (1 << 14)) break; }
      }
    }
    __syncthreads();

    // ---- consume rh ----
    if (fast) {
      inv_l1();
      const uint4v* bb = (const uint4v*)(rhbuf + (size_t)r0 * H_);
      uint4v rv[4];
      #pragma unroll
      for (int i = 0; i < 4; ++i) rv[i] = bb[tid + i * 256];
      #pragma unroll
      for (int i = 0; i < 4; ++i)
        *(uint4v*)&h_lds[(tid >> 6) + i * 4][(tid & 63) * 8] = rv[i];
    } else {
      unsigned long long rtmp[8];
      unsigned long long* bb = (unsigned long long*)(rhbuf + (size_t)r0 * H_)
                               + (tid >> 7) * 128 + (tid & 127);
      #pragma unroll
      for (int i = 0; i < 8; ++i)
        rtmp[i] = __hip_atomic_load(bb + i * 256,
                                    __ATOMIC_RELAXED, __HIP_MEMORY_SCOPE_AGENT);
      #pragma unroll
      for (int i = 0; i < 8; ++i) {
        int g = tid + i * 256;
        *(unsigned long long*)&h_lds[g >> 7][(g & 127) * 4] = rtmp[i];
      }
    }
    __syncthreads();

    // ---- phase B ----
    f32x4 acc2 = {0.f,0.f,0.f,0.f};
    {
      const unsigned short* rrow = &h_lds[l16][0];
      #pragma unroll
      for (int k = 0; k < 16; ++k) {
        short8 ar = *(const short8*)(rrow + k * 32 + lhi * 8);
        acc2 = __builtin_amdgcn_mfma_f32_16x16x32_bf16(ar, uhr[k], acc2, 0, 0, 0);
      }
    }
    #pragma unroll
    for (int i = 0; i < 4; ++i) {
      int lrow = lhi * 4 + i;
      float hh = tanhf(acc2[i] + xhc[i] + cbh);
      float hn = gh4[i] + z4[i] * hh;
      pub[lrow][lcol] = f2bf(hn);
    }
    __syncthreads();
    {
      int row = tid >> 4, c4 = (tid & 15) * 4;
      unsigned long long v = *(const unsigned long long*)&pub[row][c4];
      unsigned long long* dst = (unsigned long long*)
          (hbuf + (size_t)(r0 + row) * H_ + c0 + c4);
      if (fast) *dst = v;
      else __hip_atomic_store(dst, v, __ATOMIC_RELAXED, __HIP_MEMORY_SCOPE_AGENT);
    }
    asm volatile("s_waitcnt vmcnt(0)" ::: "memory");
    __syncthreads();
    if (tid == 0) {
      if (fast) *myfast = (int)(base + FBASE + 2 * t + 2);
      else __hip_atomic_store(myslow, (int)(base + FBASE + 2 * t + 2),
                              __ATOMIC_RELAXED, __HIP_MEMORY_SCOPE_AGENT);
    }

    // ---- S3: issue x_{t+2} prefetch (R3 position); bubble xh_next ----
    {
      int tn = (t + 2 < T_) ? (t + 2) : (T_ - 1);
      const float4* xs = (const float4*)(x + ((size_t)tn * B_ + r0) * D_);
      #pragma unroll
      for (int i = 0; i < 8; ++i) {
        int g = tid + i * 256;
        xr4[i] = xs[(g >> 7) * 128 + (g & 127)];
      }
    }
    {
      const unsigned short* xrow = &x_lds[p ^ 1][l16][0];
      #pragma unroll
      for (int k = 0; k < 16; ++k) {
        int ko = k * 32 + lhi * 8;
        short8 ax = *(const short8*)(xrow + ko);
        short8 wh = *(const short8*)(WTh + l16 * 512 + ko);
        xhn = __builtin_amdgcn_mfma_f32_16x16x32_bf16(ax, wh, xhn, 0, 0, 0);
      }
    }
    // ---- wait barrier 2 ----
    if (tid < GRP) {
      int lim = 0;
      if (fast) {
        const volatile unsigned* p2 = (const volatile unsigned*)(grpff + tid * 32);
        for (;;) {
          inv_l1();
          if (ready(*p2, base + FBASE + 2 * t + 2)) break;
          if (++lim > (1 << 14)) break;
        }
      } else {
        int* p2 = slowf + tid * 32;
        while (!ready((unsigned)__hip_atomic_load(p2, __ATOMIC_RELAXED,
                                                  __HIP_MEMORY_SCOPE_AGENT),
                      base + FBASE + 2 * t + 2))
          { if (++lim > (1 << 14)) break; }
      }
    }
    __syncthreads();

    // ---- consume h ----
    if (fast) {
      inv_l1();
      const uint4v* bb = (const uint4v*)(hbuf + (size_t)r0 * H_);
      uint4v hv[4];
      #pragma unroll
      for (int i = 0; i < 4; ++i) hv[i] = bb[tid + i * 256];
      #pragma unroll
      for (int i = 0; i < 4; ++i)
        *(uint4v*)&h_lds[(tid >> 6) + i * 4][(tid & 63) * 8] = hv[i];
    } else {
      unsigned long long htmp[8];
      unsigned long long* bb = (unsigned long long*)(hbuf + (size_t)r0 * H_)
                               + (tid >> 7) * 128 + (tid & 127);
      #pragma unroll
      for (int i = 0; i < 8; ++i)
        htmp[i] = __hip_atomic_load(bb + i * 256,
                                    __ATOMIC_RELAXED, __HIP_MEMORY_SCOPE_AGENT);
      #pragma unroll
      for (int i = 0; i < 8; ++i) {
        int g = tid + i * 256;
        *(unsigned long long*)&h_lds[g >> 7][(g & 127) * 4] = htmp[i];
      }
    }
    xzc = xzn; xrc = xrn; xhc = xhn;
    __syncthreads();
  }

  // ---- fused FC epilogue ----
  if (wid < 2) {
    const int cfc = cg * 32 + wid * 16 + l16;
    f32x4 acc = {0.f,0.f,0.f,0.f};
    const unsigned short* hrow = &h_lds[l16][0];
    #pragma unroll
    for (int k0 = 0; k0 < 512; k0 += 32) {
      int ko = k0 + lhi * 8;
      short8 ah = *(const short8*)(hrow + ko);
      short8 bw;
      #pragma unroll
      for (int j = 0; j < 8; ++j)
        bw[j] = (short)f2bf(fcw[(size_t)(ko + j) * O_ + cfc]);
      acc = __builtin_amdgcn_mfma_f32_16x16x32_bf16(ah, bw, acc, 0, 0, 0);
    }
    float bb = fcb[cfc];
    #pragma unroll
    for (int i = 0; i < 4; ++i)
      out[(size_t)(r0 + lhi * 4 + i) * O_ + cfc] = acc[i] + bb;
  }
}

extern "C" void kernel_launch(void* const* d_in, const int* in_sizes, int n_in,
                              void* d_out, int out_size, void* d_ws, size_t ws_size,
                              hipStream_t stream)
{
  const float* x    = (const float*)d_in[0];
  const float* w_z  = (const float*)d_in[1];
  const float* b_z  = (const float*)d_in[2];
  const float* u_z  = (const float*)d_in[3];
  const float* ub_z = (const float*)d_in[4];
  const float* w_r  = (const float*)d_in[5];
  const float* b_r  = (const float*)d_in[6];
  const float* u_r  = (const float*)d_in[7];
  const float* ub_r = (const float*)d_in[8];
  const float* w_h  = (const float*)d_in[9];
  const float* b_h  = (const float*)d_in[10];
  const float* u_h  = (const float*)d_in[11];
  const float* ub_h = (const float*)d_in[12];
  const float* fc_w = (const float*)d_in[13];
  const float* fc_b = (const float*)d_in[14];
  float* out = (float*)d_out;

  char* ws = (char*)d_ws;
  unsigned short* WT = (unsigned short*)ws;  ws += (size_t)1536 * 512 * 2;
  unsigned short* UT = (unsigned short*)ws;  ws += (size_t)1536 * 512 * 2;
  float* cb = (float*)ws;                    ws += 1536 * 4;
  unsigned short* hbuf = (unsigned short*)ws;  ws += (size_t)B_ * H_ * 2;
  unsigned short* rhbuf = (unsigned short*)ws; ws += (size_t)B_ * H_ * 2;
  ws = (char*)(((size_t)ws + 255) & ~(size_t)255);
  int* bar = (int*)ws;

  prep_kernel<<<3072, 256, 0, stream>>>(w_z, u_z, w_r, u_r, w_h, u_h,
                                        b_z, ub_z, b_r, ub_r, b_h, ub_h,
                                        WT, UT, cb, bar);
  gru_scan<<<NWG, 256, 0, stream>>>(x, WT, UT, cb, hbuf, rhbuf, bar,
                                    fc_w, fc_b, out);
}

// Round 11
// 4484.532 us; speedup vs baseline: 1.2882x; 1.2882x over previous
//
#include <hip/hip_runtime.h>

// GRU T=512 B=256 D=512 H=512 O=256
// R11: back to the PROVEN R3 configuration (groups of 8 consecutive wgids,
// AGENT-scope/MALL exchange). New lever: if ws_size permits (~814MB), a
// prepass GEMM computes XP = x@W{z,r,h} for ALL timesteps (f32, stored in the
// scan's exact MFMA C/D fragment layout), removing all in-loop x@W work
// (48 MFMA + 192KB/wg/step W-stream) from the serial scan. Otherwise a
// bit-exact R3 fallback (folded x@W) runs. FC fused into the scan epilogue.

#define T_ 512
#define B_ 256
#define D_ 512
#define H_ 512
#define O_ 256

#define NWG 128
#define ROWS 16
#define GC 64
#define GRP 8

typedef __attribute__((ext_vector_type(8))) short short8;
typedef __attribute__((ext_vector_type(4))) float f32x4;

__device__ __forceinline__ unsigned short f2bf(float f) {
  unsigned u = __float_as_uint(f);
  u = (u + 0x7FFFu + ((u >> 16) & 1u)) >> 16;   // RNE
  return (unsigned short)u;
}
__device__ __forceinline__ float bf2f(unsigned short h) {
  return __uint_as_float(((unsigned)h) << 16);
}

// ---- prep: transpose weights to N-major bf16, combine biases, zero flags
__global__ void prep_kernel(const float* wz, const float* uz,
                            const float* wr, const float* ur,
                            const float* wh, const float* uh,
                            const float* bz, const float* ubz,
                            const float* br, const float* ubr,
                            const float* bh, const float* ubh,
                            unsigned short* WT, unsigned short* UT,
                            float* cb, int* bar)
{
  int idx = blockIdx.x * 256 + threadIdx.x;
  if (idx < 1536 * 512) {
    int n = idx >> 9;
    int k = idx & 511;
    int g = n >> 9;
    int c = n & 511;
    const float* w = (g == 0) ? wz : (g == 1) ? wr : wh;
    const float* u = (g == 0) ? uz : (g == 1) ? ur : uh;
    WT[idx] = f2bf(w[k * H_ + c]);   // WT[n][k] = W[k][n]
    UT[idx] = f2bf(u[k * H_ + c]);
  }
  if (idx < 1536) {
    int g = idx >> 9, c = idx & 511;
    const float* b  = (g == 0) ? bz  : (g == 1) ? br  : bh;
    const float* ub = (g == 0) ? ubz : (g == 1) ? ubr : ubh;
    cb[idx] = b[c] + ub[c];
  }
  if (idx < 4096) bar[idx] = 0;   // 16 groups x 8 slots x 32-int stride
}

// ---- prepass: XP[t][bg][gate][col 0..511][row 0..15] (f32) = x_t @ W_gate
// One wg per (t,bg,cg): 16 rows x 64 cols x 3 gates. W register-resident.
__global__ __launch_bounds__(256, 1) void xw_prepass(
    const float* __restrict__ x,
    const unsigned short* __restrict__ WT,
    float* __restrict__ XP)
{
  __shared__ __align__(16) unsigned short x_lds[ROWS][520];
  const int id = blockIdx.x;            // t*128 + bg*8 + cg
  const int t  = id >> 7;
  const int bg = (id >> 3) & 15;
  const int cg = id & 7;
  const int tid = threadIdx.x;
  const int wid = tid >> 6;
  const int lane = tid & 63;
  const int l16 = lane & 15;
  const int lhi = lane >> 4;
  const int r0 = bg * ROWS;
  const int ct = cg * GC + wid * 16;
  const int gcz = ct + l16;

  const unsigned short* WTz = WT + (size_t)(ct)        * 512;
  const unsigned short* WTr = WT + (size_t)(512 + ct)  * 512;
  const unsigned short* WTh = WT + (size_t)(1024 + ct) * 512;

  // W -> registers (48 short8)
  short8 wz[16], wr[16], wh[16];
  #pragma unroll
  for (int k = 0; k < 16; ++k) {
    const int off = l16 * 512 + k * 32 + lhi * 8;
    wz[k] = *(const short8*)(WTz + off);
    wr[k] = *(const short8*)(WTr + off);
    wh[k] = *(const short8*)(WTh + off);
  }
  // stage x_t rows -> bf16 LDS
  {
    const float4* xs = (const float4*)(x + ((size_t)t * B_ + r0) * D_);
    #pragma unroll
    for (int i = 0; i < 8; ++i) {
      int g = tid + i * 256;
      float4 v = xs[(g >> 7) * 128 + (g & 127)];
      unsigned short tmp[4] = { f2bf(v.x), f2bf(v.y), f2bf(v.z), f2bf(v.w) };
      *(unsigned long long*)&x_lds[g >> 7][(g & 127) * 4] = *(unsigned long long*)tmp;
    }
  }
  __syncthreads();

  f32x4 az = {0.f,0.f,0.f,0.f}, ar = {0.f,0.f,0.f,0.f}, ah = {0.f,0.f,0.f,0.f};
  {
    const unsigned short* xrow = &x_lds[l16][0];
    #pragma unroll
    for (int k = 0; k < 16; ++k) {
      short8 ax = *(const short8*)(xrow + k * 32 + lhi * 8);
      az = __builtin_amdgcn_mfma_f32_16x16x32_bf16(ax, wz[k], az, 0, 0, 0);
      ar = __builtin_amdgcn_mfma_f32_16x16x32_bf16(ax, wr[k], ar, 0, 0, 0);
      ah = __builtin_amdgcn_mfma_f32_16x16x32_bf16(ax, wh[k], ah, 0, 0, 0);
    }
  }
  // store in fragment layout: 16B per lane per gate
  float* base = XP + ((size_t)(t * 16 + bg) * 3) * 8192;
  *(f32x4*)(base + ((size_t)0 * 512 + gcz) * 16 + lhi * 4) = az;
  *(f32x4*)(base + ((size_t)1 * 512 + gcz) * 16 + lhi * 4) = ar;
  *(f32x4*)(base + ((size_t)2 * 512 + gcz) * 16 + lhi * 4) = ah;
}

// ============ scan variant A: prepass-fed (no in-loop x@W) ============
__global__ __launch_bounds__(256, 1) void gru_scan_pre(
    const unsigned short* __restrict__ UT,
    const float* __restrict__ cb,
    const float* __restrict__ XP,
    unsigned short* hbuf, unsigned short* rhbuf, int* bar,
    const float* __restrict__ fcw, const float* __restrict__ fcb,
    float* __restrict__ out)
{
  __shared__ __align__(16) unsigned short h_lds[ROWS][520];
  __shared__ __align__(8)  unsigned short pub[ROWS][GC];

  const int tid = threadIdx.x;
  const int wid = tid >> 6;
  const int lane = tid & 63;
  const int l16 = lane & 15;
  const int lhi = lane >> 4;

  const int wgid = blockIdx.x;
  const int bg = wgid >> 3;
  const int cg = wgid & 7;
  const int r0 = bg * ROWS;
  const int c0 = cg * GC;

  int* slots  = bar + bg * 256;
  int* myslot = slots + cg * 32;

  const int ct = c0 + wid * 16;
  const int gcz = ct + l16;
  const int lcol = ct - c0 + l16;
  const unsigned short* UTz = UT + (size_t)(ct)        * 512;
  const unsigned short* UTr = UT + (size_t)(512 + ct)  * 512;
  const unsigned short* UTh = UT + (size_t)(1024 + ct) * 512;
  const float cbz = cb[gcz];
  const float cbr = cb[512 + gcz];
  const float cbh = cb[1024 + gcz];

  short8 uzr[16], urr[16], uhr[16];
  #pragma unroll
  for (int k = 0; k < 16; ++k) {
    const int off = l16 * 512 + k * 32 + lhi * 8;
    uzr[k] = *(const short8*)(UTz + off);
    urr[k] = *(const short8*)(UTr + off);
    uhr[k] = *(const short8*)(UTh + off);
  }

  // prologue: h = 0; load XP[0]
  #pragma unroll
  for (int i = 0; i < 8; ++i) {
    int g = tid + i * 256;
    *(unsigned long long*)&h_lds[g >> 7][(g & 127) * 4] = 0ull;
  }
  f32x4 xzc, xrc, xhc, xzn, xrn, xhn;
  {
    const float* bxp = XP + ((size_t)(0 * 16 + bg) * 3) * 8192;
    xzc = *(const f32x4*)(bxp + ((size_t)0 * 512 + gcz) * 16 + lhi * 4);
    xrc = *(const f32x4*)(bxp + ((size_t)1 * 512 + gcz) * 16 + lhi * 4);
    xhc = *(const f32x4*)(bxp + ((size_t)2 * 512 + gcz) * 16 + lhi * 4);
  }
  __syncthreads();

  for (int t = 0; t < T_; ++t) {
    // ---- phase A: h@Uz, h@Ur ----
    f32x4 accz = {0.f,0.f,0.f,0.f};
    f32x4 accr = {0.f,0.f,0.f,0.f};
    {
      const unsigned short* hrow = &h_lds[l16][0];
      #pragma unroll
      for (int k = 0; k < 16; ++k) {
        short8 ahh = *(const short8*)(hrow + k * 32 + lhi * 8);
        accz = __builtin_amdgcn_mfma_f32_16x16x32_bf16(ahh, uzr[k], accz, 0, 0, 0);
        accr = __builtin_amdgcn_mfma_f32_16x16x32_bf16(ahh, urr[k], accr, 0, 0, 0);
      }
    }
    f32x4 z4, gh4;
    #pragma unroll
    for (int i = 0; i < 4; ++i) {
      int lrow = lhi * 4 + i;
      float h_old = bf2f(h_lds[lrow][gcz]);
      float zv = 1.f / (1.f + __expf(-(accz[i] + xzc[i] + cbz)));
      float rv = 1.f / (1.f + __expf(-(accr[i] + xrc[i] + cbr)));
      z4[i]  = zv;
      gh4[i] = (1.f - zv) * h_old;
      pub[lrow][lcol] = f2bf(rv * h_old);
    }
    __syncthreads();
    // publish rh (coalesced 8B/thread, AGENT)
    {
      int row = tid >> 4, c4 = (tid & 15) * 4;
      unsigned long long v = *(const unsigned long long*)&pub[row][c4];
      __hip_atomic_store((unsigned long long*)
          (rhbuf + (size_t)(r0 + row) * H_ + c0 + c4), v,
          __ATOMIC_RELAXED, __HIP_MEMORY_SCOPE_AGENT);
    }
    asm volatile("s_waitcnt vmcnt(0)" ::: "memory");
    __syncthreads();
    if (tid == 0)
      __hip_atomic_store(myslot, 2 * t + 1,
                         __ATOMIC_RELAXED, __HIP_MEMORY_SCOPE_AGENT);

    // ---- XP[t+1] prefetch (in flight during barrier wait) ----
    {
      int tn = (t + 1 < T_) ? (t + 1) : (T_ - 1);
      const float* bxp = XP + ((size_t)(tn * 16 + bg) * 3) * 8192;
      xzn = *(const f32x4*)(bxp + ((size_t)0 * 512 + gcz) * 16 + lhi * 4);
      xrn = *(const f32x4*)(bxp + ((size_t)1 * 512 + gcz) * 16 + lhi * 4);
      xhn = *(const f32x4*)(bxp + ((size_t)2 * 512 + gcz) * 16 + lhi * 4);
    }
    // ---- wait barrier 1 (bounded) ----
    if (tid < GRP) {
      int lim = 0;
      while (__hip_atomic_load(slots + tid * 32, __ATOMIC_RELAXED,
                               __HIP_MEMORY_SCOPE_AGENT) < 2 * t + 1)
        { if (++lim > (1 << 16)) break; }
    }
    __syncthreads();

    // ---- consume rh ----
    {
      unsigned long long rtmp[8];
      const unsigned long long* bb = (const unsigned long long*)(rhbuf + (size_t)r0 * H_);
      #pragma unroll
      for (int i = 0; i < 8; ++i) {
        int g = tid + i * 256;
        rtmp[i] = __hip_atomic_load(bb + (g >> 7) * 128 + (g & 127) + 0,
                                    __ATOMIC_RELAXED, __HIP_MEMORY_SCOPE_AGENT);
      }
      #pragma unroll
      for (int i = 0; i < 8; ++i) {
        int g = tid + i * 256;
        *(unsigned long long*)&h_lds[g >> 7][(g & 127) * 4] = rtmp[i];
      }
    }
    __syncthreads();

    // ---- phase B: rh@Uh; h update ----
    f32x4 acc2 = {0.f,0.f,0.f,0.f};
    {
      const unsigned short* rrow = &h_lds[l16][0];
      #pragma unroll
      for (int k = 0; k < 16; ++k) {
        short8 arr = *(const short8*)(rrow + k * 32 + lhi * 8);
        acc2 = __builtin_amdgcn_mfma_f32_16x16x32_bf16(arr, uhr[k], acc2, 0, 0, 0);
      }
    }
    #pragma unroll
    for (int i = 0; i < 4; ++i) {
      int lrow = lhi * 4 + i;
      float hh = tanhf(acc2[i] + xhc[i] + cbh);
      float hn = gh4[i] + z4[i] * hh;
      pub[lrow][lcol] = f2bf(hn);
    }
    __syncthreads();
    {
      int row = tid >> 4, c4 = (tid & 15) * 4;
      unsigned long long v = *(const unsigned long long*)&pub[row][c4];
      __hip_atomic_store((unsigned long long*)
          (hbuf + (size_t)(r0 + row) * H_ + c0 + c4), v,
          __ATOMIC_RELAXED, __HIP_MEMORY_SCOPE_AGENT);
    }
    asm volatile("s_waitcnt vmcnt(0)" ::: "memory");
    __syncthreads();
    if (tid == 0)
      __hip_atomic_store(myslot, 2 * t + 2,
                         __ATOMIC_RELAXED, __HIP_MEMORY_SCOPE_AGENT);

    // ---- wait barrier 2 (bounded) ----
    if (tid < GRP) {
      int lim = 0;
      while (__hip_atomic_load(slots + tid * 32, __ATOMIC_RELAXED,
                               __HIP_MEMORY_SCOPE_AGENT) < 2 * t + 2)
        { if (++lim > (1 << 16)) break; }
    }
    __syncthreads();

    // ---- consume h ----
    {
      unsigned long long htmp[8];
      const unsigned long long* bb = (const unsigned long long*)(hbuf + (size_t)r0 * H_);
      #pragma unroll
      for (int i = 0; i < 8; ++i) {
        int g = tid + i * 256;
        htmp[i] = __hip_atomic_load(bb + (g >> 7) * 128 + (g & 127),
                                    __ATOMIC_RELAXED, __HIP_MEMORY_SCOPE_AGENT);
      }
      #pragma unroll
      for (int i = 0; i < 8; ++i) {
        int g = tid + i * 256;
        *(unsigned long long*)&h_lds[g >> 7][(g & 127) * 4] = htmp[i];
      }
    }
    xzc = xzn; xrc = xrn; xhc = xhn;
    __syncthreads();
  }

  // ---- fused FC epilogue ----
  if (wid < 2) {
    const int cfc = cg * 32 + wid * 16 + l16;
    f32x4 acc = {0.f,0.f,0.f,0.f};
    const unsigned short* hrow = &h_lds[l16][0];
    #pragma unroll
    for (int k0 = 0; k0 < 512; k0 += 32) {
      int ko = k0 + lhi * 8;
      short8 ahh = *(const short8*)(hrow + ko);
      short8 bw;
      #pragma unroll
      for (int j = 0; j < 8; ++j)
        bw[j] = (short)f2bf(fcw[(size_t)(ko + j) * O_ + cfc]);
      acc = __builtin_amdgcn_mfma_f32_16x16x32_bf16(ahh, bw, acc, 0, 0, 0);
    }
    float bb = fcb[cfc];
    #pragma unroll
    for (int i = 0; i < 4; ++i)
      out[(size_t)(r0 + lhi * 4 + i) * O_ + cfc] = acc[i] + bb;
  }
}

// ============ scan variant B: R3-exact folded x@W fallback ============
__global__ __launch_bounds__(256, 1) void gru_scan_fold(
    const float* __restrict__ x,
    const unsigned short* __restrict__ WT,
    const unsigned short* __restrict__ UT,
    const float* __restrict__ cb,
    unsigned short* hbuf, unsigned short* rhbuf, int* bar,
    const float* __restrict__ fcw, const float* __restrict__ fcb,
    float* __restrict__ out)
{
  __shared__ __align__(16) unsigned short x_lds[2][ROWS][520];
  __shared__ __align__(16) unsigned short h_lds[ROWS][520];

  const int wgid = blockIdx.x;
  const int bg = wgid >> 3;
  const int cg = wgid & 7;
  const int r0 = bg * ROWS;
  const int c0 = cg * GC;
  const int tid = threadIdx.x;
  const int wid = tid >> 6;
  const int lane = tid & 63;
  const int l16 = lane & 15;
  const int lhi = lane >> 4;

  int* slots  = bar + bg * 256;
  int* myslot = slots + cg * 32;

  const int ct = c0 + wid * 16;
  const unsigned short* WTz = WT + (size_t)(ct)        * 512;
  const unsigned short* WTr = WT + (size_t)(512 + ct)  * 512;
  const unsigned short* WTh = WT + (size_t)(1024 + ct) * 512;
  const unsigned short* UTz = UT + (size_t)(ct)        * 512;
  const unsigned short* UTr = UT + (size_t)(512 + ct)  * 512;
  const unsigned short* UTh = UT + (size_t)(1024 + ct) * 512;

  const int gcz  = ct + l16;
  const float cbz = cb[gcz];
  const float cbr = cb[512 + gcz];
  const float cbh = cb[1024 + gcz];

  short8 uzr[16], urr[16], uhr[16];
  #pragma unroll
  for (int k = 0; k < 16; ++k) {
    const int off = l16 * 512 + k * 32 + lhi * 8;
    uzr[k] = *(const short8*)(UTz + off);
    urr[k] = *(const short8*)(UTr + off);
    uhr[k] = *(const short8*)(UTh + off);
  }

  float4 xr4[8];
  {
    const float4* xs = (const float4*)(x + (size_t)r0 * D_);
    #pragma unroll
    for (int i = 0; i < 8; ++i) {
      int g = tid + i * 256;
      float4 v = xs[(g >> 7) * 128 + (g & 127)];
      unsigned short tmp[4] = { f2bf(v.x), f2bf(v.y), f2bf(v.z), f2bf(v.w) };
      *(unsigned long long*)&x_lds[0][g >> 7][(g & 127) * 4] = *(unsigned long long*)tmp;
      *(unsigned long long*)&h_lds[g >> 7][(g & 127) * 4] = 0ull;
    }
    const float4* xs1 = (const float4*)(x + ((size_t)B_ + r0) * D_);
    #pragma unroll
    for (int i = 0; i < 8; ++i) {
      int g = tid + i * 256;
      xr4[i] = xs1[(g >> 7) * 128 + (g & 127)];
    }
  }
  __syncthreads();

  f32x4 xzc = {0.f,0.f,0.f,0.f}, xrc = {0.f,0.f,0.f,0.f}, xhc = {0.f,0.f,0.f,0.f};
  {
    const unsigned short* xrow = &x_lds[0][l16][0];
    #pragma unroll
    for (int k = 0; k < 16; ++k) {
      int ko = k * 32 + lhi * 8;
      short8 ax = *(const short8*)(xrow + ko);
      int boff = l16 * 512 + ko;
      short8 wz = *(const short8*)(WTz + boff);
      short8 wr = *(const short8*)(WTr + boff);
      short8 wh = *(const short8*)(WTh + boff);
      xzc = __builtin_amdgcn_mfma_f32_16x16x32_bf16(ax, wz, xzc, 0, 0, 0);
      xrc = __builtin_amdgcn_mfma_f32_16x16x32_bf16(ax, wr, xrc, 0, 0, 0);
      xhc = __builtin_amdgcn_mfma_f32_16x16x32_bf16(ax, wh, xhc, 0, 0, 0);
    }
  }

  for (int t = 0; t < T_; ++t) {
    const int p = t & 1;
    f32x4 accz = {0.f,0.f,0.f,0.f};
    f32x4 accr = {0.f,0.f,0.f,0.f};
    {
      const unsigned short* hrow = &h_lds[l16][0];
      #pragma unroll
      for (int k = 0; k < 16; ++k) {
        short8 ah = *(const short8*)(hrow + k * 32 + lhi * 8);
        accz = __builtin_amdgcn_mfma_f32_16x16x32_bf16(ah, uzr[k], accz, 0, 0, 0);
        accr = __builtin_amdgcn_mfma_f32_16x16x32_bf16(ah, urr[k], accr, 0, 0, 0);
      }
    }
    f32x4 z4, gh4;
    #pragma unroll
    for (int i = 0; i < 4; ++i) {
      int lrow = lhi * 4 + i;
      float h_old = bf2f(h_lds[lrow][gcz]);
      float zv = 1.f / (1.f + __expf(-(accz[i] + xzc[i] + cbz)));
      float rv = 1.f / (1.f + __expf(-(accr[i] + xrc[i] + cbr)));
      z4[i]  = zv;
      gh4[i] = (1.f - zv) * h_old;
      __hip_atomic_store(rhbuf + (size_t)(r0 + lrow) * H_ + gcz, f2bf(rv * h_old),
                         __ATOMIC_RELAXED, __HIP_MEMORY_SCOPE_AGENT);
    }
    __syncthreads();
    if (tid == 0)
      __hip_atomic_store(myslot, 2 * t + 1, __ATOMIC_RELAXED, __HIP_MEMORY_SCOPE_AGENT);

    f32x4 xzn = {0.f,0.f,0.f,0.f}, xrn = {0.f,0.f,0.f,0.f}, xhn = {0.f,0.f,0.f,0.f};
    {
      #pragma unroll
      for (int i = 0; i < 8; ++i) {
        int g = tid + i * 256;
        float4 v = xr4[i];
        unsigned short tmp[4] = { f2bf(v.x), f2bf(v.y), f2bf(v.z), f2bf(v.w) };
        *(unsigned long long*)&x_lds[p ^ 1][g >> 7][(g & 127) * 4] = *(unsigned long long*)tmp;
      }
    }
    __syncthreads();
    {
      const unsigned short* xrow = &x_lds[p ^ 1][l16][0];
      #pragma unroll
      for (int k = 0; k < 16; ++k) {
        short8 ax = *(const short8*)(xrow + k * 32 + lhi * 8);
        short8 wz = *(const short8*)(WTz + l16 * 512 + k * 32 + lhi * 8);
        xzn = __builtin_amdgcn_mfma_f32_16x16x32_bf16(ax, wz, xzn, 0, 0, 0);
      }
    }
    if (tid < GRP) {
      int lim = 0;
      while (__hip_atomic_load(slots + tid * 32, __ATOMIC_RELAXED,
                               __HIP_MEMORY_SCOPE_AGENT) < 2 * t + 1)
        { if (++lim > (1 << 16)) break; }
    }
    __syncthreads();

    {
      unsigned long long rtmp[8];
      const unsigned long long* rs = (const unsigned long long*)(rhbuf + (size_t)r0 * H_);
      #pragma unroll
      for (int i = 0; i < 8; ++i) {
        int g = tid + i * 256;
        rtmp[i] = __hip_atomic_load(rs + (g >> 7) * 128 + (g & 127),
                                    __ATOMIC_RELAXED, __HIP_MEMORY_SCOPE_AGENT);
      }
      {
        const unsigned short* xrow = &x_lds[p ^ 1][l16][0];
        #pragma unroll
        for (int k = 0; k < 16; ++k) {
          short8 ax = *(const short8*)(xrow + k * 32 + lhi * 8);
          short8 wr = *(const short8*)(WTr + l16 * 512 + k * 32 + lhi * 8);
          xrn = __builtin_amdgcn_mfma_f32_16x16x32_bf16(ax, wr, xrn, 0, 0, 0);
        }
      }
      #pragma unroll
      for (int i = 0; i < 8; ++i) {
        int g = tid + i * 256;
        *(unsigned long long*)&h_lds[g >> 7][(g & 127) * 4] = rtmp[i];
      }
    }
    __syncthreads();

    f32x4 acc2 = {0.f,0.f,0.f,0.f};
    {
      const unsigned short* rrow = &h_lds[l16][0];
      #pragma unroll
      for (int k = 0; k < 16; ++k) {
        short8 ar = *(const short8*)(rrow + k * 32 + lhi * 8);
        acc2 = __builtin_amdgcn_mfma_f32_16x16x32_bf16(ar, uhr[k], acc2, 0, 0, 0);
      }
    }
    {
      #pragma unroll
      for (int i = 0; i < 4; ++i) {
        int lrow = lhi * 4 + i;
        float hh = tanhf(acc2[i] + xhc[i] + cbh);
        float hn = gh4[i] + z4[i] * hh;
        __hip_atomic_store(hbuf + (size_t)(r0 + lrow) * H_ + gcz, f2bf(hn),
                           __ATOMIC_RELAXED, __HIP_MEMORY_SCOPE_AGENT);
      }
    }
    __syncthreads();
    if (tid == 0)
      __hip_atomic_store(myslot, 2 * t + 2, __ATOMIC_RELAXED, __HIP_MEMORY_SCOPE_AGENT);

    {
      int tn = (t + 2 < T_) ? (t + 2) : (T_ - 1);
      const float4* xs = (const float4*)(x + ((size_t)tn * B_ + r0) * D_);
      #pragma unroll
      for (int i = 0; i < 8; ++i) {
        int g = tid + i * 256;
        xr4[i] = xs[(g >> 7) * 128 + (g & 127)];
      }
    }
    if (tid < GRP) {
      int lim = 0;
      while (__hip_atomic_load(slots + tid * 32, __ATOMIC_RELAXED,
                               __HIP_MEMORY_SCOPE_AGENT) < 2 * t + 2)
        { if (++lim > (1 << 16)) break; }
    }
    __syncthreads();

    {
      unsigned long long htmp[8];
      const unsigned long long* hs = (const unsigned long long*)(hbuf + (size_t)r0 * H_);
      #pragma unroll
      for (int i = 0; i < 8; ++i) {
        int g = tid + i * 256;
        htmp[i] = __hip_atomic_load(hs + (g >> 7) * 128 + (g & 127),
                                    __ATOMIC_RELAXED, __HIP_MEMORY_SCOPE_AGENT);
      }
      {
        const unsigned short* xrow = &x_lds[p ^ 1][l16][0];
        #pragma unroll
        for (int k = 0; k < 16; ++k) {
          short8 ax = *(const short8*)(xrow + k * 32 + lhi * 8);
          short8 wh = *(const short8*)(WTh + l16 * 512 + k * 32 + lhi * 8);
          xhn = __builtin_amdgcn_mfma_f32_16x16x32_bf16(ax, wh, xhn, 0, 0, 0);
        }
      }
      #pragma unroll
      for (int i = 0; i < 8; ++i) {
        int g = tid + i * 256;
        *(unsigned long long*)&h_lds[g >> 7][(g & 127) * 4] = htmp[i];
      }
    }
    xzc = xzn; xrc = xrn; xhc = xhn;
    __syncthreads();
  }

  if (wid < 2) {
    const int cfc = cg * 32 + wid * 16 + l16;
    f32x4 acc = {0.f,0.f,0.f,0.f};
    const unsigned short* hrow = &h_lds[l16][0];
    #pragma unroll
    for (int k0 = 0; k0 < 512; k0 += 32) {
      int ko = k0 + lhi * 8;
      short8 ah = *(const short8*)(hrow + ko);
      short8 bw;
      #pragma unroll
      for (int j = 0; j < 8; ++j)
        bw[j] = (short)f2bf(fcw[(size_t)(ko + j) * O_ + cfc]);
      acc = __builtin_amdgcn_mfma_f32_16x16x32_bf16(ah, bw, acc, 0, 0, 0);
    }
    float bb = fcb[cfc];
    #pragma unroll
    for (int i = 0; i < 4; ++i)
      out[(size_t)(r0 + lhi * 4 + i) * O_ + cfc] = acc[i] + bb;
  }
}

extern "C" void kernel_launch(void* const* d_in, const int* in_sizes, int n_in,
                              void* d_out, int out_size, void* d_ws, size_t ws_size,
                              hipStream_t stream)
{
  const float* x    = (const float*)d_in[0];
  const float* w_z  = (const float*)d_in[1];
  const float* b_z  = (const float*)d_in[2];
  const float* u_z  = (const float*)d_in[3];
  const float* ub_z = (const float*)d_in[4];
  const float* w_r  = (const float*)d_in[5];
  const float* b_r  = (const float*)d_in[6];
  const float* u_r  = (const float*)d_in[7];
  const float* ub_r = (const float*)d_in[8];
  const float* w_h  = (const float*)d_in[9];
  const float* b_h  = (const float*)d_in[10];
  const float* u_h  = (const float*)d_in[11];
  const float* ub_h = (const float*)d_in[12];
  const float* fc_w = (const float*)d_in[13];
  const float* fc_b = (const float*)d_in[14];
  float* out = (float*)d_out;

  char* ws0 = (char*)d_ws;
  char* ws = ws0;
  unsigned short* WT = (unsigned short*)ws;  ws += (size_t)1536 * 512 * 2;
  unsigned short* UT = (unsigned short*)ws;  ws += (size_t)1536 * 512 * 2;
  float* cb = (float*)ws;                    ws += 1536 * 4;
  unsigned short* hbuf = (unsigned short*)ws;  ws += (size_t)B_ * H_ * 2;
  unsigned short* rhbuf = (unsigned short*)ws; ws += (size_t)B_ * H_ * 2;
  ws = (char*)(((size_t)ws - (size_t)ws0 + 255 & ~(size_t)255) + (size_t)ws0);
  int* bar = (int*)ws;                       ws += 16384 * 4;
  ws = (char*)(((size_t)ws - (size_t)ws0 + 255 & ~(size_t)255) + (size_t)ws0);
  float* XP = (float*)ws;
  const size_t xp_bytes = (size_t)T_ * 16 * 3 * 8192 * 4;   // 805 MB
  const size_t need = (size_t)(ws - ws0) + xp_bytes;
  const bool pre = (ws_size >= need);

  prep_kernel<<<3072, 256, 0, stream>>>(w_z, u_z, w_r, u_r, w_h, u_h,
                                        b_z, ub_z, b_r, ub_r, b_h, ub_h,
                                        WT, UT, cb, bar);
  if (pre) {
    xw_prepass<<<T_ * 128, 256, 0, stream>>>(x, WT, XP);
    gru_scan_pre<<<NWG, 256, 0, stream>>>(UT, cb, XP, hbuf, rhbuf, bar,
                                          fc_w, fc_b, out);
  } else {
    gru_scan_fold<<<NWG, 256, 0, stream>>>(x, WT, UT, cb, hbuf, rhbuf, bar,
                                           fc_w, fc_b, out);
  }
}